// Round 3
// baseline (1706.246 us; speedup 1.0000x reference)
//
#include <hip/hip_runtime.h>
#include <math.h>

// Problem constants: L=4096, B=8, D=1024, Z=256, H=2048, N=64, C=512
// M = L*B = 32768 flattened rows (r = l*B + b), E = D+Z+H+D = 4352.

typedef __attribute__((ext_vector_type(4))) float f32x4;
typedef __attribute__((ext_vector_type(8))) _Float16 half8;
typedef __attribute__((ext_vector_type(8))) short short8;
typedef __attribute__((ext_vector_type(4))) unsigned short u16x4;

__device__ __forceinline__ unsigned short f2h(float f){ _Float16 h=(_Float16)f; unsigned short u; __builtin_memcpy(&u,&h,2); return u; }
__device__ __forceinline__ float h2f(unsigned short u){ _Float16 h; __builtin_memcpy(&h,&u,2); return (float)h; }
__device__ __forceinline__ float sigm(float x){ return 1.f/(1.f+expf(-x)); }
__device__ __forceinline__ float siluf(float x){ return x/(1.f+expf(-x)); }

__device__ __forceinline__ void gl16(const void* g, void* l){
  __builtin_amdgcn_global_load_lds((__attribute__((address_space(1))) unsigned int*)g,
                                   (__attribute__((address_space(3))) unsigned int*)l, 16, 0, 0);
}

// ---------- weight transpose + f32->f16 : src (K,N) -> dst (N,K) ----------
__global__ __launch_bounds__(256) void k_tcvt(const float* __restrict__ src, unsigned short* __restrict__ dst, int K, int N){
  __shared__ float tile[32][33];
  int k0 = blockIdx.x<<5, n0 = blockIdx.y<<5;
  int tx = threadIdx.x & 31, ty = threadIdx.x >> 5;
  #pragma unroll
  for(int i=0;i<4;i++){ int kk = ty + i*8; tile[kk][tx] = src[(size_t)(k0+kk)*N + n0 + tx]; }
  __syncthreads();
  #pragma unroll
  for(int i=0;i<4;i++){ int nn = ty + i*8; dst[(size_t)(n0+nn)*K + k0 + tx] = f2h(tile[tx][nn]); }
}

// ---------- EMA kernel taps: ckT[j][d], j<256, f16 ----------
__global__ __launch_bounds__(256) void k_coeffs(const float* __restrict__ damping, const float* __restrict__ decay,
    const float* __restrict__ expan, const float* __restrict__ kproj, unsigned short* __restrict__ ckT){
  int d = blockIdx.x;
  __shared__ float cC[64], cLQ[64];
  int t = threadIdx.x;
  if(t < 64){
    float p = sigm(damping[d*64+t]);
    float qw = 1.f - p*sigm(decay[d*64+t]);
    cC[t] = p*expan[d*64+t]*kproj[d*64+t]*0.125f;   // 1/sqrt(64)
    cLQ[t] = logf(qw);
  }
  __syncthreads();
  float s = 0.f;
  #pragma unroll 8
  for(int n=0;n<64;n++) s += cC[n]*expf((float)t*cLQ[n]);
  ckT[t*1024 + d] = f2h(s);
}

// ---------- rotary bias: bias[i][j] = ra[i,:] . rb[j,:] ----------
__global__ __launch_bounds__(256) void k_bias(const float* __restrict__ alpha, const float* __restrict__ beta, float* __restrict__ bias){
  int i = blockIdx.x;
  __shared__ float ra[256];
  int t = threadIdx.x;
  {
    int zz = t & 127;
    float fr = expf(-(logf(10000.f)/128.f)*(float)zz);
    float ang = (float)i*fr;
    float sv, cv; sincosf(ang, &sv, &cv);
    float a1 = alpha[zz], a2 = alpha[128+zz];
    ra[t] = (t<128) ? (a1*cv - a2*sv) : (a2*cv + a1*sv);
  }
  __syncthreads();
  for(int j0 = t; j0 < 512; j0 += 256){
    float acc = 0.f;
    for(int zz=0; zz<128; zz++){
      float fr = expf(-(logf(10000.f)/128.f)*(float)zz);
      float ang = (float)j0*fr;
      float sv, cv; sincosf(ang, &sv, &cv);
      float b1 = beta[zz], b2 = beta[128+zz];
      acc += ra[zz]*(b1*cv - b2*sv) + ra[128+zz]*(b2*cv + b1*sv);
    }
    bias[(size_t)i*512 + j0] = acc;
  }
}

// ---------- scalenorm -> xnh (f16) ----------
__global__ __launch_bounds__(256) void k_scalenorm(const float* __restrict__ x, const float* __restrict__ g,
    unsigned short* __restrict__ xnh){
  int r = blockIdx.x, t = threadIdx.x;
  const float4* xr = (const float4*)(x + (size_t)r*1024);
  float4 v = xr[t];
  float ss = v.x*v.x + v.y*v.y + v.z*v.z + v.w*v.w;
  #pragma unroll
  for(int m=32;m;m>>=1) ss += __shfl_xor(ss, m);
  __shared__ float wsum[4];
  if((t&63)==0) wsum[t>>6] = ss;
  __syncthreads();
  float tot = wsum[0]+wsum[1]+wsum[2]+wsum[3];
  float sc = rsqrtf(tot*(1.f/1024.f) + 1e-6f)*g[0];
  u16x4 p; p[0]=f2h(v.x*sc); p[1]=f2h(v.y*sc); p[2]=f2h(v.z*sc); p[3]=f2h(v.w*sc);
  *(u16x4*)(xnh + (size_t)r*1024 + t*4) = p;
}

// ---------- truncated causal conv (256 taps) + silu(ema + xn*res_w) fused ----------
__global__ __launch_bounds__(256) void k_conv(const unsigned short* __restrict__ xnh,
    const unsigned short* __restrict__ ckT, const float* __restrict__ resw, unsigned short* __restrict__ mxh){
  __shared__ unsigned short xs[384][34];
  __shared__ unsigned short ks[256][34];
  int l0 = blockIdx.x<<7, d0 = blockIdx.y<<5, b = blockIdx.z;
  int t = threadIdx.x;
  int cpair = (t&15)<<1, rbase = t>>4;
  #pragma unroll
  for(int p2=0;p2<16;p2++){
    int j = p2*16 + rbase;
    *(unsigned int*)&ks[j][cpair] = *(const unsigned int*)(ckT + (size_t)j*1024 + d0 + cpair);
  }
  #pragma unroll
  for(int p2=0;p2<24;p2++){
    int rowi = p2*16 + rbase;
    int l = l0 - 256 + rowi;
    unsigned int v = 0u;
    if(l >= 0) v = *(const unsigned int*)(xnh + ((size_t)(l*8+b))*1024 + d0 + cpair);
    *(unsigned int*)&xs[rowi][cpair] = v;
  }
  __syncthreads();
  int d = t&31, tg = t>>5;
  int base = 256 + tg*16;
  float rv = resw[d0+d];
  float wv[16], acc[16], xv0[16];
  #pragma unroll
  for(int i=0;i<16;i++){ wv[i] = h2f(xs[base+i][d]); xv0[i] = wv[i]; acc[i]=0.f; }
  #pragma unroll 16
  for(int j=0;j<256;j++){
    float kv = h2f(ks[j][d]);
    #pragma unroll
    for(int i=0;i<16;i++) acc[i] += kv*wv[i];
    #pragma unroll
    for(int i=15;i>0;i--) wv[i] = wv[i-1];
    wv[0] = h2f(xs[base-j-1][d]);
  }
  #pragma unroll
  for(int i=0;i<16;i++){
    int l = l0 + tg*16 + i;
    size_t idx = ((size_t)(l*8+b))*1024 + d0 + d;
    float pre = acc[i] + xv0[i]*rv;
    mxh[idx] = f2h(siluf(pre));
  }
}

// ---------- m97-style 128x128 f16 MFMA GEMM, A (M,K), Bt (N,K), fused epilogues ----------
// EPI 0: value = silu(acc+bias) -> o0 (ld N)
// EPI 1: base split: rw=sigmoid->o0, qk=silu->o1, gate=silu->o2, inter f16 -> oh
// EPI 2: frame=silu(acc+bh+inter[oh]); out = x + rw*(frame-x) -> of
template<int EPI>
__global__ __launch_bounds__(256,2) void k_gemm(const unsigned short* __restrict__ A, const unsigned short* __restrict__ Bt,
    const float* __restrict__ bias, int NT, int K, int N,
    unsigned short* __restrict__ o0, unsigned short* __restrict__ o1, unsigned short* __restrict__ o2,
    unsigned short* __restrict__ oh, float* __restrict__ of,
    const float* __restrict__ x4, const unsigned short* __restrict__ rw4){
  __shared__ unsigned short As[4096], Bs[4096];
  int nwg = gridDim.x, id = blockIdx.x;
  int q = nwg>>3, r8 = nwg&7;
  int xcd = id&7, rest = id>>3;
  int sid = (xcd < r8 ? xcd*(q+1) : r8*(q+1) + (xcd-r8)*q) + rest;
  int mt = sid/NT, nt = sid - mt*NT;
  int t = threadIdx.x, w = t>>6, lane = t&63;
  int wr = (w>>1)<<6, wc = (w&1)<<6;
  const unsigned short* ag = A + ((size_t)(mt*128 + w*32 + (lane>>2)))*K + ((lane&3)<<3);
  const unsigned short* bg = Bt + ((size_t)(nt*128 + w*32 + (lane>>2)))*K + ((lane&3)<<3);
  f32x4 acc[4][4] = {};
  for(int k0=0;k0<K;k0+=32){
    gl16(ag, &As[(w*32)*32]);
    gl16(ag + (size_t)16*K, &As[(w*32+16)*32]);
    gl16(bg, &Bs[(w*32)*32]);
    gl16(bg + (size_t)16*K, &Bs[(w*32+16)*32]);
    ag += 32; bg += 32;
    __syncthreads();
    int fr = lane&15, kq = (lane>>4)<<3;
    half8 af[4], bfr[4];
    #pragma unroll
    for(int i=0;i<4;i++){
      af[i] = *(const half8*)&As[(wr+i*16+fr)*32 + kq];
      bfr[i] = *(const half8*)&Bs[(wc+i*16+fr)*32 + kq];
    }
    #pragma unroll
    for(int i=0;i<4;i++)
      #pragma unroll
      for(int j2=0;j2<4;j2++)
        acc[i][j2] = __builtin_amdgcn_mfma_f32_16x16x32_f16(af[i], bfr[j2], acc[i][j2], 0,0,0);
    __syncthreads();
  }
  int fr = lane&15;
  #pragma unroll
  for(int i=0;i<4;i++)
    #pragma unroll
    for(int j2=0;j2<4;j2++){
      int cc = nt*128 + wc + j2*16 + fr;
      float bcol = bias[cc];
      #pragma unroll
      for(int e=0;e<4;e++){
        int rr = mt*128 + wr + i*16 + ((lane>>4)<<2) + e;
        float v = acc[i][j2][e] + bcol;
        if(EPI==0){
          o0[(size_t)rr*N + cc] = f2h(siluf(v));
        } else if(EPI==1){
          if(cc < 1024)      o0[(size_t)rr*1024 + cc] = f2h(sigm(v));
          else if(cc < 1280) o1[(size_t)rr*256 + (cc-1024)] = f2h(siluf(v));
          else if(cc < 3328) o2[(size_t)rr*2048 + (cc-1280)] = f2h(siluf(v));
          else               oh[(size_t)rr*1024 + (cc-3328)] = f2h(v);
        } else {
          size_t idx = (size_t)rr*1024 + cc;
          float f = siluf(v + h2f(oh[idx]));
          float xv = x4[idx];
          of[idx] = xv + h2f(rw4[idx])*(f - xv);
        }
      }
    }
}

// ---------- scores = q@k^T /16 + bias, lower-triangle tiles only ----------
__global__ __launch_bounds__(256,2) void k_qk(const unsigned short* __restrict__ qk, const float* __restrict__ qkw,
    const float* __restrict__ qkbv, const float* __restrict__ bias, float* __restrict__ scores){
  int c = blockIdx.x, pi = blockIdx.y;
  int ti = (int)((sqrtf(8.f*pi+1.f)-1.f)*0.5f + 1e-4f);
  int tj = pi - ti*(ti+1)/2;
  int bb = c>>3, lc = c&7;
  __shared__ unsigned short As[4096], Bs[4096];
  __shared__ float w0[256], b0s[256], w1[256], b1s[256];
  int t = threadIdx.x;
  w0[t]=qkw[t]; w1[t]=qkw[256+t]; b0s[t]=qkbv[t]; b1s[t]=qkbv[256+t];
  __syncthreads();
  int w = t>>6, lane = t&63;
  int wr = (w>>1)<<6, wc = (w&1)<<6;
  int row = t>>1, zo = (t&1)<<4;
  f32x4 acc[4][4] = {};
  for(int k0=0;k0<256;k0+=32){
    {
      size_t rA = ((size_t)((lc*512 + ti*128 + row)*8 + bb))*256;
      short8 v0 = *(const short8*)(qk + rA + k0 + zo);
      short8 v1 = *(const short8*)(qk + rA + k0 + zo + 8);
      short8 q0, q1;
      #pragma unroll
      for(int jj=0;jj<8;jj++){ int z=k0+zo+jj;   q0[jj]=(short)f2h(h2f((unsigned short)v0[jj])*w0[z]+b0s[z]); }
      #pragma unroll
      for(int jj=0;jj<8;jj++){ int z=k0+zo+8+jj; q1[jj]=(short)f2h(h2f((unsigned short)v1[jj])*w0[z]+b0s[z]); }
      *(short8*)&As[row*32+zo] = q0; *(short8*)&As[row*32+zo+8] = q1;
      size_t rB = ((size_t)((lc*512 + tj*128 + row)*8 + bb))*256;
      v0 = *(const short8*)(qk + rB + k0 + zo);
      v1 = *(const short8*)(qk + rB + k0 + zo + 8);
      #pragma unroll
      for(int jj=0;jj<8;jj++){ int z=k0+zo+jj;   q0[jj]=(short)f2h(h2f((unsigned short)v0[jj])*w1[z]+b1s[z]); }
      #pragma unroll
      for(int jj=0;jj<8;jj++){ int z=k0+zo+8+jj; q1[jj]=(short)f2h(h2f((unsigned short)v1[jj])*w1[z]+b1s[z]); }
      *(short8*)&Bs[row*32+zo] = q0; *(short8*)&Bs[row*32+zo+8] = q1;
    }
    __syncthreads();
    int fr = lane&15, kq = (lane>>4)<<3;
    half8 af[4], bfr[4];
    #pragma unroll
    for(int i=0;i<4;i++){
      af[i] = *(const half8*)&As[(wr+i*16+fr)*32 + kq];
      bfr[i] = *(const half8*)&Bs[(wc+i*16+fr)*32 + kq];
    }
    #pragma unroll
    for(int i=0;i<4;i++)
      #pragma unroll
      for(int j2=0;j2<4;j2++)
        acc[i][j2] = __builtin_amdgcn_mfma_f32_16x16x32_f16(af[i], bfr[j2], acc[i][j2], 0,0,0);
    __syncthreads();
  }
  int fr = lane&15;
  #pragma unroll
  for(int i=0;i<4;i++)
    #pragma unroll
    for(int j2=0;j2<4;j2++)
      #pragma unroll
      for(int e=0;e<4;e++){
        int si = ti*128 + wr + i*16 + ((lane>>4)<<2) + e;
        int sj = tj*128 + wc + j2*16 + fr;
        scores[((size_t)c*512 + si)*512 + sj] = acc[i][j2][e]*(1.f/16.f) + bias[(size_t)si*512 + sj];
      }
}

// ---------- causal row softmax (512 wide), writes P f16 (zeros above diagonal) ----------
__global__ __launch_bounds__(256) void k_softmax(const float* __restrict__ s, unsigned short* __restrict__ P){
  int rowg = (blockIdx.x<<2) + (threadIdx.x>>6);
  int lane = threadIdx.x & 63;
  int i = rowg & 511;
  const float4* s4 = (const float4*)(s + (size_t)rowg*512);
  float4 a = s4[lane*2];
  float4 b2 = s4[lane*2+1];
  float vals[8] = {a.x,a.y,a.z,a.w,b2.x,b2.y,b2.z,b2.w};
  float mx = -3e38f;
  #pragma unroll
  for(int q=0;q<8;q++){
    int j = (lane<<3)+q;
    if(j > i) vals[q] = -3e38f;
    mx = fmaxf(mx, vals[q]);
  }
  #pragma unroll
  for(int m=32;m;m>>=1) mx = fmaxf(mx, __shfl_xor(mx, m));
  float sum = 0.f;
  #pragma unroll
  for(int q=0;q<8;q++){ vals[q] = expf(vals[q]-mx); sum += vals[q]; }
  #pragma unroll
  for(int m=32;m;m>>=1) sum += __shfl_xor(sum, m);
  float inv = 1.f/sum;
  short8 o;
  #pragma unroll
  for(int q=0;q<8;q++) o[q] = (short)f2h(vals[q]*inv);
  *(short8*)(P + (size_t)rowg*512 + (lane<<3)) = o;
}

// ---------- weighted = P @ V, fused: gw := (P@V) * gw  (in-place over gate) ----------
__global__ __launch_bounds__(256,2) void k_pv(const unsigned short* __restrict__ P, const unsigned short* __restrict__ val,
    unsigned short* __restrict__ gw){
  int mt = blockIdx.x, nt = blockIdx.y, c = blockIdx.z;
  int bb = c>>3, lc = c&7;
  __shared__ unsigned short As[4096];
  __shared__ unsigned short Bs[4096];
  int t = threadIdx.x, w = t>>6, lane = t&63;
  int wr = (w>>1)<<6, wc = (w&1)<<6;
  f32x4 acc[4][4] = {};
  int kmax = (mt+1)*128;           // causal: only j < (mt+1)*128 contribute (P is 0 beyond row)
  const unsigned short* ag = P + ((size_t)(c*512 + mt*128 + w*32 + (lane>>2)))*512 + ((lane&3)<<3);
  int h0 = nt*128;
  int bj = w*8 + (lane>>4);
  int bh2 = (lane&15)<<3;
  for(int k0=0;k0<kmax;k0+=32){
    gl16(ag, &As[(w*32)*32]);
    gl16(ag + (size_t)16*512, &As[(w*32+16)*32]);
    {
      int j0 = k0 + bj;
      size_t r0 = (size_t)((lc*512 + j0)*8 + bb);
      gl16(val + r0*2048 + h0 + bh2, &Bs[(w*8)*128]);
      size_t r1 = (size_t)((lc*512 + j0 + 4)*8 + bb);
      gl16(val + r1*2048 + h0 + bh2, &Bs[(w*8+4)*128]);
    }
    ag += 32;
    __syncthreads();
    int fr = lane&15, kq = (lane>>4)<<3;
    half8 af[4], bfr[4];
    #pragma unroll
    for(int i=0;i<4;i++) af[i] = *(const half8*)&As[(wr+i*16+fr)*32 + kq];
    #pragma unroll
    for(int j2=0;j2<4;j2++){
      half8 hv;
      #pragma unroll
      for(int ii=0;ii<8;ii++){ _Float16 xh; unsigned short u = Bs[(kq+ii)*128 + wc + j2*16 + fr]; __builtin_memcpy(&xh,&u,2); hv[ii]=xh; }
      bfr[j2] = hv;
    }
    #pragma unroll
    for(int i=0;i<4;i++)
      #pragma unroll
      for(int j2=0;j2<4;j2++)
        acc[i][j2] = __builtin_amdgcn_mfma_f32_16x16x32_f16(af[i], bfr[j2], acc[i][j2], 0,0,0);
    __syncthreads();
  }
  int fr = lane&15;
  #pragma unroll
  for(int i=0;i<4;i++)
    #pragma unroll
    for(int j2=0;j2<4;j2++)
      #pragma unroll
      for(int e=0;e<4;e++){
        int ii = mt*128 + wr + i*16 + ((lane>>4)<<2) + e;
        size_t rr = (size_t)((lc*512 + ii)*8 + bb);
        int hh = h0 + wc + j2*16 + fr;
        float gv = h2f(gw[rr*2048 + hh]);
        gw[rr*2048 + hh] = f2h(acc[i][j2][e]*gv);
      }
}

extern "C" void kernel_launch(void* const* d_in, const int* in_sizes, int n_in,
                              void* d_out, int out_size, void* d_ws, size_t ws_size,
                              hipStream_t stream) {
  const float* x    = (const float*)d_in[0];
  const float* g    = (const float*)d_in[1];
  const float* Wv   = (const float*)d_in[2];
  const float* bv   = (const float*)d_in[3];
  const float* Wmx  = (const float*)d_in[4];
  const float* bmx  = (const float*)d_in[5];
  const float* Wh   = (const float*)d_in[6];
  const float* bh   = (const float*)d_in[7];
  const float* qkw  = (const float*)d_in[8];
  const float* qkb  = (const float*)d_in[9];
  const float* damping = (const float*)d_in[10];
  const float* decay   = (const float*)d_in[11];
  const float* expan   = (const float*)d_in[12];
  const float* kproj   = (const float*)d_in[13];
  const float* resw    = (const float*)d_in[14];
  const float* alpha   = (const float*)d_in[15];
  const float* beta    = (const float*)d_in[16];
  (void)in_sizes; (void)n_in; (void)out_size; (void)ws_size;

  char* ws = (char*)d_ws;
  // Workspace layout (peak ~482 MB):
  unsigned short* valh  = (unsigned short*)(ws + 0);             // 134MB [g0, pv]
  unsigned short* gwh   = (unsigned short*)(ws + 134217728ull);  // 134MB gate [g1,pv] then wg in-place [pv,g2]
  unsigned short* xnh   = (unsigned short*)(ws + 268435456ull);  // 67MB  [sn, conv]
  unsigned short* rwh   = xnh;                                   //       rw [g1, g2] (xnh dead)
  unsigned short* mxh   = (unsigned short*)(ws + 335544320ull);  // 67MB  [conv, g1]
  unsigned short* Pmat  = mxh;                                   // 33.5MB P [sm, pv] (mxh dead)
  unsigned short* interh= (unsigned short*)(ws + 402653184ull);  // 67MB  [g1, g2]
  unsigned short* qkh   = (unsigned short*)(ws + 469762048ull);  // 16.7MB [g1, qk]
  unsigned short* WvT   = (unsigned short*)(ws + 486539264ull);  // 4MB
  unsigned short* WmxT  = (unsigned short*)(ws + 490733568ull);  // 8.5MB
  unsigned short* WhT   = (unsigned short*)(ws + 499646464ull);  // 4MB
  unsigned short* ckT   = (unsigned short*)(ws + 503840768ull);  // 0.5MB
  float* biasb          = (float*)(ws + 504365056ull);           // 1MB -> end ~482MB
  float* outp  = (float*)d_out;
  float* scores = (float*)d_out;   // 67MB of d_out reused as scores [qk, sm]; g2 overwrites all of d_out

  k_tcvt<<<dim3(32,64), dim3(256), 0, stream>>>(Wv,  WvT, 1024, 2048);
  k_tcvt<<<dim3(32,136), dim3(256), 0, stream>>>(Wmx, WmxT, 1024, 4352);
  k_tcvt<<<dim3(64,32), dim3(256), 0, stream>>>(Wh,  WhT, 2048, 1024);
  k_coeffs<<<dim3(1024), dim3(256), 0, stream>>>(damping, decay, expan, kproj, ckT);
  k_bias<<<dim3(512), dim3(256), 0, stream>>>(alpha, beta, biasb);
  k_scalenorm<<<dim3(32768), dim3(256), 0, stream>>>(x, g, xnh);
  k_gemm<0><<<dim3(4096), dim3(256), 0, stream>>>(xnh, WvT, bv, 16, 1024, 2048,
      valh, (unsigned short*)0, (unsigned short*)0, (unsigned short*)0, (float*)0, (const float*)0, (const unsigned short*)0);
  k_conv<<<dim3(32,32,8), dim3(256), 0, stream>>>(xnh, ckT, resw, mxh);
  k_gemm<1><<<dim3(8704), dim3(256), 0, stream>>>(mxh, WmxT, bmx, 34, 1024, 4352,
      rwh, qkh, gwh, interh, (float*)0, (const float*)0, (const unsigned short*)0);
  k_qk<<<dim3(64,10), dim3(256), 0, stream>>>(qkh, qkw, qkb, biasb, scores);
  k_softmax<<<dim3(8192), dim3(256), 0, stream>>>(scores, Pmat);
  k_pv<<<dim3(4,16,64), dim3(256), 0, stream>>>(Pmat, valh, gwh);
  k_gemm<2><<<dim3(2048), dim3(256), 0, stream>>>(gwh, WhT, bh, 8, 2048, 1024,
      (unsigned short*)0, (unsigned short*)0, (unsigned short*)0, interh, outp, x, rwh);
}

// Round 5
// 1688.301 us; speedup vs baseline: 1.0106x; 1.0106x over previous
//
#include <hip/hip_runtime.h>
#include <math.h>

// Problem constants: L=4096, B=8, D=1024, Z=256, H=2048, N=64, C=512
// M = L*B = 32768 flattened rows (r = l*B + b), E = D+Z+H+D = 4352.

typedef __attribute__((ext_vector_type(4))) float f32x4;
typedef __attribute__((ext_vector_type(8))) _Float16 half8;
typedef __attribute__((ext_vector_type(8))) short short8;
typedef __attribute__((ext_vector_type(4))) unsigned short u16x4;

__device__ __forceinline__ unsigned short f2h(float f){ _Float16 h=(_Float16)f; unsigned short u; __builtin_memcpy(&u,&h,2); return u; }
__device__ __forceinline__ float h2f(unsigned short u){ _Float16 h; __builtin_memcpy(&h,&u,2); return (float)h; }
__device__ __forceinline__ float sigm(float x){ return 1.f/(1.f+expf(-x)); }
__device__ __forceinline__ float siluf(float x){ return x/(1.f+expf(-x)); }

__device__ __forceinline__ void gl16(const void* g, void* l){
  __builtin_amdgcn_global_load_lds((__attribute__((address_space(1))) unsigned int*)g,
                                   (__attribute__((address_space(3))) unsigned int*)l, 16, 0, 0);
}

// ---------- weight transpose + f32->f16 : src (K,N) -> dst (N,K) ----------
__global__ __launch_bounds__(256) void k_tcvt(const float* __restrict__ src, unsigned short* __restrict__ dst, int K, int N){
  __shared__ float tile[32][33];
  int k0 = blockIdx.x<<5, n0 = blockIdx.y<<5;
  int tx = threadIdx.x & 31, ty = threadIdx.x >> 5;
  #pragma unroll
  for(int i=0;i<4;i++){ int kk = ty + i*8; tile[kk][tx] = src[(size_t)(k0+kk)*N + n0 + tx]; }
  __syncthreads();
  #pragma unroll
  for(int i=0;i<4;i++){ int nn = ty + i*8; dst[(size_t)(n0+nn)*K + k0 + tx] = f2h(tile[tx][nn]); }
}

// ---------- EMA kernel taps: ckT[j][d], j<192, f16 ----------
__global__ __launch_bounds__(256) void k_coeffs(const float* __restrict__ damping, const float* __restrict__ decay,
    const float* __restrict__ expan, const float* __restrict__ kproj, unsigned short* __restrict__ ckT){
  int d = blockIdx.x;
  __shared__ float cC[64], cLQ[64];
  int t = threadIdx.x;
  if(t < 64){
    float p = sigm(damping[d*64+t]);
    float qw = 1.f - p*sigm(decay[d*64+t]);
    cC[t] = p*expan[d*64+t]*kproj[d*64+t]*0.125f;   // 1/sqrt(64)
    cLQ[t] = logf(qw);
  }
  __syncthreads();
  float s = 0.f;
  #pragma unroll 8
  for(int n=0;n<64;n++) s += cC[n]*expf((float)t*cLQ[n]);
  ckT[t*1024 + d] = f2h(s);
}

// ---------- rotary bias: bias[i][j] = ra[i,:] . rb[j,:] ----------
__global__ __launch_bounds__(256) void k_bias(const float* __restrict__ alpha, const float* __restrict__ beta, float* __restrict__ bias){
  int i = blockIdx.x;
  __shared__ float ra[256];
  int t = threadIdx.x;
  {
    int zz = t & 127;
    float fr = expf(-(logf(10000.f)/128.f)*(float)zz);
    float ang = (float)i*fr;
    float sv, cv; sincosf(ang, &sv, &cv);
    float a1 = alpha[zz], a2 = alpha[128+zz];
    ra[t] = (t<128) ? (a1*cv - a2*sv) : (a2*cv + a1*sv);
  }
  __syncthreads();
  for(int j0 = t; j0 < 512; j0 += 256){
    float acc = 0.f;
    for(int zz=0; zz<128; zz++){
      float fr = expf(-(logf(10000.f)/128.f)*(float)zz);
      float ang = (float)j0*fr;
      float sv, cv; sincosf(ang, &sv, &cv);
      float b1 = beta[zz], b2 = beta[128+zz];
      acc += ra[zz]*(b1*cv - b2*sv) + ra[128+zz]*(b2*cv + b1*sv);
    }
    bias[(size_t)i*512 + j0] = acc;
  }
}

// ---------- scalenorm -> xnh (f16) ----------
__global__ __launch_bounds__(256) void k_scalenorm(const float* __restrict__ x, const float* __restrict__ g,
    unsigned short* __restrict__ xnh){
  int r = blockIdx.x, t = threadIdx.x;
  const float4* xr = (const float4*)(x + (size_t)r*1024);
  float4 v = xr[t];
  float ss = v.x*v.x + v.y*v.y + v.z*v.z + v.w*v.w;
  #pragma unroll
  for(int m=32;m;m>>=1) ss += __shfl_xor(ss, m);
  __shared__ float wsum[4];
  if((t&63)==0) wsum[t>>6] = ss;
  __syncthreads();
  float tot = wsum[0]+wsum[1]+wsum[2]+wsum[3];
  float sc = rsqrtf(tot*(1.f/1024.f) + 1e-6f)*g[0];
  u16x4 p; p[0]=f2h(v.x*sc); p[1]=f2h(v.y*sc); p[2]=f2h(v.z*sc); p[3]=f2h(v.w*sc);
  *(u16x4*)(xnh + (size_t)r*1024 + t*4) = p;
}

// ---------- truncated causal conv (192 taps) + silu(ema + xn*res_w) fused ----------
__global__ __launch_bounds__(256) void k_conv(const unsigned short* __restrict__ xnh,
    const unsigned short* __restrict__ ckT, const float* __restrict__ resw, unsigned short* __restrict__ mxh){
  __shared__ unsigned short xs[384][34];
  __shared__ unsigned short ks[192][34];
  int l0 = blockIdx.x<<7, d0 = blockIdx.y<<5, b = blockIdx.z;
  int t = threadIdx.x;
  int cpair = (t&15)<<1, rbase = t>>4;
  #pragma unroll
  for(int p2=0;p2<12;p2++){
    int j = p2*16 + rbase;
    *(unsigned int*)&ks[j][cpair] = *(const unsigned int*)(ckT + (size_t)j*1024 + d0 + cpair);
  }
  #pragma unroll
  for(int p2=0;p2<24;p2++){
    int rowi = p2*16 + rbase;
    int l = l0 - 256 + rowi;
    unsigned int v = 0u;
    if(l >= 0) v = *(const unsigned int*)(xnh + ((size_t)(l*8+b))*1024 + d0 + cpair);
    *(unsigned int*)&xs[rowi][cpair] = v;
  }
  __syncthreads();
  int d = t&31, tg = t>>5;
  int base = 256 + tg*16;
  float rv = resw[d0+d];
  float wv[16], acc[16], xv0[16];
  #pragma unroll
  for(int i=0;i<16;i++){ wv[i] = h2f(xs[base+i][d]); xv0[i] = wv[i]; acc[i]=0.f; }
  #pragma unroll 16
  for(int j=0;j<192;j++){
    float kv = h2f(ks[j][d]);
    #pragma unroll
    for(int i=0;i<16;i++) acc[i] += kv*wv[i];
    #pragma unroll
    for(int i=15;i>0;i--) wv[i] = wv[i-1];
    wv[0] = h2f(xs[base-j-1][d]);
  }
  #pragma unroll
  for(int i=0;i<16;i++){
    int l = l0 + tg*16 + i;
    size_t idx = ((size_t)(l*8+b))*1024 + d0 + d;
    float pre = acc[i] + xv0[i]*rv;
    mxh[idx] = f2h(siluf(pre));
  }
}

// ---------- 256x256 BK=64 deep-pipelined f16 MFMA GEMM (T2 swizzle + T4 counted vmcnt + T5) ----------
// A (M,K) f16 row-major, Bt (N,K) f16 row-major. 512 threads = 8 waves (2M x 4N).
// LDS (dynamic 128KB): [A0|A1|B0|B1], each 16384 halves = 256 rows x 64 halves (128B rows).
// Swizzle: half-index ^= (row&7)<<3 on reads; source-col pre-swizzled for linear gl16 dest.
// EPI 0: value = silu(acc+bias) -> o0 (ld N)
// EPI 1: base split: rw=sigmoid->o0, qk=silu->o1, gate=silu->o2, inter f16 -> oh
// EPI 2: frame=silu(acc+bh+inter[oh]); out = x + rw*(frame-x) -> of
template<int EPI>
__global__ __launch_bounds__(512,2) void k_gemm8(const unsigned short* __restrict__ A, const unsigned short* __restrict__ Bt,
    const float* __restrict__ bias, int NT, int K, int N,
    unsigned short* __restrict__ o0, unsigned short* __restrict__ o1, unsigned short* __restrict__ o2,
    unsigned short* __restrict__ oh, float* __restrict__ of,
    const float* __restrict__ x4, const unsigned short* __restrict__ rw4){
  extern __shared__ unsigned short lds[];
  int nwg = gridDim.x, id = blockIdx.x;
  int q8 = nwg>>3, r8 = nwg&7;
  int xcd = id&7, rest = id>>3;
  int sid = (xcd < r8 ? xcd*(q8+1) : r8*(q8+1) + (xcd-r8)*q8) + rest;
  int mt = sid/NT, nt = sid - mt*NT;
  int t = threadIdx.x;
  int w = t>>6, lane = t&63;
  int wm = w>>2, wn = w&3;
  int mrow0 = mt<<8, ncol0 = nt<<8;
  // staging: wave w owns segments w*4+j (j=0..3) of each buffer; seg = 8 rows x 128B (linear 1KB).
  int a8 = lane>>3;                         // row within 8-row segment
  int scol = (((lane&7) ^ a8) << 3);        // pre-swizzled source column (elements)
  const unsigned short* Ag = A + (size_t)(mrow0 + w*32 + a8)*K + scol;
  const unsigned short* Bg = Bt + (size_t)(ncol0 + w*32 + a8)*K + scol;
  unsigned short* Ad = lds + w*2048;        // + buf*16384 + j*512 (halves)
  unsigned short* Bd = lds + 32768 + w*2048;

  f32x4 acc[8][4] = {};
  int NTk = K>>6;
  // prologue: stage K-tile 0 -> buf0
  #pragma unroll
  for(int j=0;j<4;j++){
    gl16(Ag + (size_t)(j*8)*K, Ad + j*512);
    gl16(Bg + (size_t)(j*8)*K, Bd + j*512);
  }
  int fr = lane&15, kq8 = (lane>>4)<<3;
  int swz = (fr&7)<<3;
  for(int kt=0; kt<NTk; ++kt){
    int cb = kt&1;
    if(kt+1 < NTk){
      int nb = (kt+1)&1;
      const unsigned short* Ags = Ag + (size_t)(kt+1)*64;
      const unsigned short* Bgs = Bg + (size_t)(kt+1)*64;
      #pragma unroll
      for(int j=0;j<4;j++){
        gl16(Ags + (size_t)(j*8)*K, Ad + nb*16384 + j*512);
        gl16(Bgs + (size_t)(j*8)*K, Bd + nb*16384 + j*512);
      }
      asm volatile("s_waitcnt vmcnt(8)" ::: "memory");   // tile kt landed; kt+1 stays in flight
    } else {
      asm volatile("s_waitcnt vmcnt(0)" ::: "memory");
    }
    __builtin_amdgcn_s_barrier();
    const unsigned short* Ab = lds + cb*16384;
    const unsigned short* Bb = lds + 32768 + cb*16384;
    #pragma unroll
    for(int qd=0; qd<4; qd++){
      const int mh = (qd>>1)<<2, nh = (qd&1)<<1;
      half8 af[4][2], bf[2][2];
      #pragma unroll
      for(int i=0;i<4;i++)
        #pragma unroll
        for(int ks=0;ks<2;ks++)
          af[i][ks] = *(const half8*)(Ab + ((((wm*128 + (mh+i)*16 + fr)*64) + ks*32 + kq8) ^ swz));
      #pragma unroll
      for(int j=0;j<2;j++)
        #pragma unroll
        for(int ks=0;ks<2;ks++)
          bf[j][ks] = *(const half8*)(Bb + ((((wn*64 + (nh+j)*16 + fr)*64) + ks*32 + kq8) ^ swz));
      __builtin_amdgcn_s_setprio(1);
      #pragma unroll
      for(int i=0;i<4;i++)
        #pragma unroll
        for(int j=0;j<2;j++){
          acc[mh+i][nh+j] = __builtin_amdgcn_mfma_f32_16x16x32_f16(af[i][0], bf[j][0], acc[mh+i][nh+j],0,0,0);
          acc[mh+i][nh+j] = __builtin_amdgcn_mfma_f32_16x16x32_f16(af[i][1], bf[j][1], acc[mh+i][nh+j],0,0,0);
        }
      __builtin_amdgcn_s_setprio(0);
      __builtin_amdgcn_s_barrier();
    }
  }
  // epilogue
  #pragma unroll
  for(int im=0; im<8; im++)
    #pragma unroll
    for(int in=0; in<4; in++){
      int cc = ncol0 + wn*64 + in*16 + fr;
      float bcol = bias[cc];
      #pragma unroll
      for(int e=0;e<4;e++){
        int rr = mrow0 + wm*128 + im*16 + ((lane>>4)<<2) + e;
        float v = acc[im][in][e] + bcol;
        if(EPI==0){
          o0[(size_t)rr*N + cc] = f2h(siluf(v));
        } else if(EPI==1){
          if(cc < 1024)      o0[(size_t)rr*1024 + cc] = f2h(sigm(v));
          else if(cc < 1280) o1[(size_t)rr*256 + (cc-1024)] = f2h(siluf(v));
          else if(cc < 3328) o2[(size_t)rr*2048 + (cc-1280)] = f2h(siluf(v));
          else               oh[(size_t)rr*1024 + (cc-3328)] = f2h(v);
        } else {
          size_t idx = (size_t)rr*1024 + cc;
          float f = siluf(v + h2f(oh[idx]));
          float xv = x4[idx];
          of[idx] = xv + h2f(rw4[idx])*(f - xv);
        }
      }
    }
}

// ---------- scores = q@k^T /16 + bias, lower-triangle tiles only ----------
__global__ __launch_bounds__(256,2) void k_qk(const unsigned short* __restrict__ qk, const float* __restrict__ qkw,
    const float* __restrict__ qkbv, const float* __restrict__ bias, float* __restrict__ scores){
  int c = blockIdx.x, pi = blockIdx.y;
  int ti = (int)((sqrtf(8.f*pi+1.f)-1.f)*0.5f + 1e-4f);
  int tj = pi - ti*(ti+1)/2;
  int bb = c>>3, lc = c&7;
  __shared__ unsigned short As[4096], Bs[4096];
  __shared__ float w0[256], b0s[256], w1[256], b1s[256];
  int t = threadIdx.x;
  w0[t]=qkw[t]; w1[t]=qkw[256+t]; b0s[t]=qkbv[t]; b1s[t]=qkbv[256+t];
  __syncthreads();
  int w = t>>6, lane = t&63;
  int wr = (w>>1)<<6, wc = (w&1)<<6;
  int row = t>>1, zo = (t&1)<<4;
  f32x4 acc[4][4] = {};
  for(int k0=0;k0<256;k0+=32){
    {
      size_t rA = ((size_t)((lc*512 + ti*128 + row)*8 + bb))*256;
      short8 v0 = *(const short8*)(qk + rA + k0 + zo);
      short8 v1 = *(const short8*)(qk + rA + k0 + zo + 8);
      short8 q0, q1;
      #pragma unroll
      for(int jj=0;jj<8;jj++){ int z=k0+zo+jj;   q0[jj]=(short)f2h(h2f((unsigned short)v0[jj])*w0[z]+b0s[z]); }
      #pragma unroll
      for(int jj=0;jj<8;jj++){ int z=k0+zo+8+jj; q1[jj]=(short)f2h(h2f((unsigned short)v1[jj])*w0[z]+b0s[z]); }
      *(short8*)&As[row*32+zo] = q0; *(short8*)&As[row*32+zo+8] = q1;
      size_t rB = ((size_t)((lc*512 + tj*128 + row)*8 + bb))*256;
      v0 = *(const short8*)(qk + rB + k0 + zo);
      v1 = *(const short8*)(qk + rB + k0 + zo + 8);
      #pragma unroll
      for(int jj=0;jj<8;jj++){ int z=k0+zo+jj;   q0[jj]=(short)f2h(h2f((unsigned short)v0[jj])*w1[z]+b1s[z]); }
      #pragma unroll
      for(int jj=0;jj<8;jj++){ int z=k0+zo+8+jj; q1[jj]=(short)f2h(h2f((unsigned short)v1[jj])*w1[z]+b1s[z]); }
      *(short8*)&Bs[row*32+zo] = q0; *(short8*)&Bs[row*32+zo+8] = q1;
    }
    __syncthreads();
    int fr = lane&15, kq = (lane>>4)<<3;
    half8 af[4], bfr[4];
    #pragma unroll
    for(int i=0;i<4;i++){
      af[i] = *(const half8*)&As[(wr+i*16+fr)*32 + kq];
      bfr[i] = *(const half8*)&Bs[(wc+i*16+fr)*32 + kq];
    }
    #pragma unroll
    for(int i=0;i<4;i++)
      #pragma unroll
      for(int j2=0;j2<4;j2++)
        acc[i][j2] = __builtin_amdgcn_mfma_f32_16x16x32_f16(af[i], bfr[j2], acc[i][j2], 0,0,0);
    __syncthreads();
  }
  int fr = lane&15;
  #pragma unroll
  for(int i=0;i<4;i++)
    #pragma unroll
    for(int j2=0;j2<4;j2++)
      #pragma unroll
      for(int e=0;e<4;e++){
        int si = ti*128 + wr + i*16 + ((lane>>4)<<2) + e;
        int sj = tj*128 + wc + j2*16 + fr;
        scores[((size_t)c*512 + si)*512 + sj] = acc[i][j2][e]*(1.f/16.f) + bias[(size_t)si*512 + sj];
      }
}

// ---------- causal row softmax (512 wide), writes P f16 (zeros above diagonal) ----------
__global__ __launch_bounds__(256) void k_softmax(const float* __restrict__ s, unsigned short* __restrict__ P){
  int rowg = (blockIdx.x<<2) + (threadIdx.x>>6);
  int lane = threadIdx.x & 63;
  int i = rowg & 511;
  const float4* s4 = (const float4*)(s + (size_t)rowg*512);
  float4 a = s4[lane*2];
  float4 b2 = s4[lane*2+1];
  float vals[8] = {a.x,a.y,a.z,a.w,b2.x,b2.y,b2.z,b2.w};
  float mx = -3e38f;
  #pragma unroll
  for(int q=0;q<8;q++){
    int j = (lane<<3)+q;
    if(j > i) vals[q] = -3e38f;
    mx = fmaxf(mx, vals[q]);
  }
  #pragma unroll
  for(int m=32;m;m>>=1) mx = fmaxf(mx, __shfl_xor(mx, m));
  float sum = 0.f;
  #pragma unroll
  for(int q=0;q<8;q++){ vals[q] = expf(vals[q]-mx); sum += vals[q]; }
  #pragma unroll
  for(int m=32;m;m>>=1) sum += __shfl_xor(sum, m);
  float inv = 1.f/sum;
  short8 o;
  #pragma unroll
  for(int q=0;q<8;q++) o[q] = (short)f2h(vals[q]*inv);
  *(short8*)(P + (size_t)rowg*512 + (lane<<3)) = o;
}

// ---------- weighted = P @ V, fused: gw := (P@V) * gw  (in-place over gate) ----------
__global__ __launch_bounds__(256,2) void k_pv(const unsigned short* __restrict__ P, const unsigned short* __restrict__ val,
    unsigned short* __restrict__ gw){
  int mt = blockIdx.x, nt = blockIdx.y, c = blockIdx.z;
  int bb = c>>3, lc = c&7;
  __shared__ unsigned short As[4096];
  __shared__ unsigned short Bs[4096];
  int t = threadIdx.x, w = t>>6, lane = t&63;
  int wr = (w>>1)<<6, wc = (w&1)<<6;
  f32x4 acc[4][4] = {};
  int kmax = (mt+1)*128;           // causal: only j < (mt+1)*128 contribute (P is 0 beyond row)
  const unsigned short* ag = P + ((size_t)(c*512 + mt*128 + w*32 + (lane>>2)))*512 + ((lane&3)<<3);
  int h0 = nt*128;
  int bj = w*8 + (lane>>4);
  int bh2 = (lane&15)<<3;
  for(int k0=0;k0<kmax;k0+=32){
    gl16(ag, &As[(w*32)*32]);
    gl16(ag + (size_t)16*512, &As[(w*32+16)*32]);
    {
      int j0 = k0 + bj;
      size_t r0 = (size_t)((lc*512 + j0)*8 + bb);
      gl16(val + r0*2048 + h0 + bh2, &Bs[(w*8)*128]);
      size_t r1 = (size_t)((lc*512 + j0 + 4)*8 + bb);
      gl16(val + r1*2048 + h0 + bh2, &Bs[(w*8+4)*128]);
    }
    ag += 32;
    __syncthreads();
    int fr = lane&15, kq = (lane>>4)<<3;
    half8 af[4], bfr[4];
    #pragma unroll
    for(int i=0;i<4;i++) af[i] = *(const half8*)&As[(wr+i*16+fr)*32 + kq];
    #pragma unroll
    for(int j2=0;j2<4;j2++){
      half8 hv;
      #pragma unroll
      for(int ii=0;ii<8;ii++){ _Float16 xh; unsigned short u = Bs[(kq+ii)*128 + wc + j2*16 + fr]; __builtin_memcpy(&xh,&u,2); hv[ii]=xh; }
      bfr[j2] = hv;
    }
    #pragma unroll
    for(int i=0;i<4;i++)
      #pragma unroll
      for(int j2=0;j2<4;j2++)
        acc[i][j2] = __builtin_amdgcn_mfma_f32_16x16x32_f16(af[i], bfr[j2], acc[i][j2], 0,0,0);
    __syncthreads();
  }
  int fr = lane&15;
  #pragma unroll
  for(int i=0;i<4;i++)
    #pragma unroll
    for(int j2=0;j2<4;j2++)
      #pragma unroll
      for(int e=0;e<4;e++){
        int ii = mt*128 + wr + i*16 + ((lane>>4)<<2) + e;
        size_t rr = (size_t)((lc*512 + ii)*8 + bb);
        int hh = h0 + wc + j2*16 + fr;
        float gv = h2f(gw[rr*2048 + hh]);
        gw[rr*2048 + hh] = f2h(acc[i][j2][e]*gv);
      }
}

extern "C" void kernel_launch(void* const* d_in, const int* in_sizes, int n_in,
                              void* d_out, int out_size, void* d_ws, size_t ws_size,
                              hipStream_t stream) {
  const float* x    = (const float*)d_in[0];
  const float* g    = (const float*)d_in[1];
  const float* Wv   = (const float*)d_in[2];
  const float* bv   = (const float*)d_in[3];
  const float* Wmx  = (const float*)d_in[4];
  const float* bmx  = (const float*)d_in[5];
  const float* Wh   = (const float*)d_in[6];
  const float* bh   = (const float*)d_in[7];
  const float* qkw  = (const float*)d_in[8];
  const float* qkb  = (const float*)d_in[9];
  const float* damping = (const float*)d_in[10];
  const float* decay   = (const float*)d_in[11];
  const float* expan   = (const float*)d_in[12];
  const float* kproj   = (const float*)d_in[13];
  const float* resw    = (const float*)d_in[14];
  const float* alpha   = (const float*)d_in[15];
  const float* beta    = (const float*)d_in[16];
  (void)in_sizes; (void)n_in; (void)out_size; (void)ws_size;

  char* ws = (char*)d_ws;
  // Workspace layout (peak ~482 MB):
  unsigned short* valh  = (unsigned short*)(ws + 0);             // 134MB [g0, pv]
  unsigned short* gwh   = (unsigned short*)(ws + 134217728ull);  // 134MB gate [g1,pv] then wg in-place [pv,g2]
  unsigned short* xnh   = (unsigned short*)(ws + 268435456ull);  // 67MB  [sn, conv]
  unsigned short* rwh   = xnh;                                   //       rw [g1, g2] (xnh dead)
  unsigned short* mxh   = (unsigned short*)(ws + 335544320ull);  // 67MB  [conv, g1]
  unsigned short* Pmat  = mxh;                                   // 33.5MB P [sm, pv] (mxh dead)
  unsigned short* interh= (unsigned short*)(ws + 402653184ull);  // 67MB  [g1, g2]
  unsigned short* qkh   = (unsigned short*)(ws + 469762048ull);  // 16.7MB [g1, qk]
  unsigned short* WvT   = (unsigned short*)(ws + 486539264ull);  // 4MB
  unsigned short* WmxT  = (unsigned short*)(ws + 490733568ull);  // 8.5MB
  unsigned short* WhT   = (unsigned short*)(ws + 499646464ull);  // 4MB
  unsigned short* ckT   = (unsigned short*)(ws + 503840768ull);  // 0.5MB
  float* biasb          = (float*)(ws + 504365056ull);           // 1MB -> end ~482MB
  float* outp  = (float*)d_out;
  float* scores = (float*)d_out;   // 67MB of d_out reused as scores [qk, sm]; g2 overwrites all of d_out

  // allow 128KB dynamic LDS for the big GEMMs (idempotent; host-side, not a stream op)
  (void)hipFuncSetAttribute(reinterpret_cast<const void*>(&k_gemm8<0>), hipFuncAttributeMaxDynamicSharedMemorySize, 131072);
  (void)hipFuncSetAttribute(reinterpret_cast<const void*>(&k_gemm8<1>), hipFuncAttributeMaxDynamicSharedMemorySize, 131072);
  (void)hipFuncSetAttribute(reinterpret_cast<const void*>(&k_gemm8<2>), hipFuncAttributeMaxDynamicSharedMemorySize, 131072);

  k_tcvt<<<dim3(32,64), dim3(256), 0, stream>>>(Wv,  WvT, 1024, 2048);
  k_tcvt<<<dim3(32,136), dim3(256), 0, stream>>>(Wmx, WmxT, 1024, 4352);
  k_tcvt<<<dim3(64,32), dim3(256), 0, stream>>>(Wh,  WhT, 2048, 1024);
  k_coeffs<<<dim3(1024), dim3(256), 0, stream>>>(damping, decay, expan, kproj, ckT);
  k_bias<<<dim3(512), dim3(256), 0, stream>>>(alpha, beta, biasb);
  k_scalenorm<<<dim3(32768), dim3(256), 0, stream>>>(x, g, xnh);
  k_gemm8<0><<<dim3(1024), dim3(512), 131072, stream>>>(xnh, WvT, bv, 8, 1024, 2048,
      valh, (unsigned short*)0, (unsigned short*)0, (unsigned short*)0, (float*)0, (const float*)0, (const unsigned short*)0);
  k_conv<<<dim3(32,32,8), dim3(256), 0, stream>>>(xnh, ckT, resw, mxh);
  k_gemm8<1><<<dim3(2176), dim3(512), 131072, stream>>>(mxh, WmxT, bmx, 17, 1024, 4352,
      rwh, qkh, gwh, interh, (float*)0, (const float*)0, (const unsigned short*)0);
  k_qk<<<dim3(64,10), dim3(256), 0, stream>>>(qkh, qkw, qkb, biasb, scores);
  k_softmax<<<dim3(8192), dim3(256), 0, stream>>>(scores, Pmat);
  k_pv<<<dim3(4,16,64), dim3(256), 0, stream>>>(Pmat, valh, gwh);
  k_gemm8<2><<<dim3(512), dim3(512), 131072, stream>>>(gwh, WhT, bh, 4, 2048, 1024,
      (unsigned short*)0, (unsigned short*)0, (unsigned short*)0, interh, outp, x, rwh);
}